// Round 5
// baseline (430.405 us; speedup 1.0000x reference)
//
#include <hip/hip_runtime.h>
#include <math.h>

#define BB   16
#define TT   1026
#define LEN  1024
#define NTOT (BB*LEN)        // 16384
#define NX   (BB*TT*64)      // 1050624 floats in x

typedef __attribute__((ext_vector_type(8))) short bf16x8;
typedef __attribute__((ext_vector_type(4))) float f32x4;

// ---- ws byte offsets ----
#define OXH   ((size_t)0)                     // XH: NX shorts
#define OXL   (OXH + (size_t)NX*2)            // XL: NX shorts
#define OW1H  (OXL + (size_t)NX*2)            // 64 l * 8192 shorts
#define OW1L  (OW1H + (size_t)64*8192*2)
#define OW2H  (OW1L + (size_t)64*8192*2)      // 64 l * 4096 shorts (pi k-order)
#define OW2L  (OW2H + (size_t)64*4096*2)
#define OVH   (OW2L + (size_t)64*4096*2)      // V = w1l .* W2, hi split (pi k-order)
#define OVL   (OVH + (size_t)64*4096*2)
#define OWLF  (OVL + (size_t)64*4096*2)       // f32 [64][64] w1_last transposed
#define ORSV  (OWLF + (size_t)64*64*4)        // f32 [64*64]
#define OPDP  (ORSV + (size_t)64*64*4)        // f32 [8][16384] logdet partials

__device__ __forceinline__ unsigned int rne16(unsigned int u) {
    return (u + 0x7FFFu + ((u >> 16) & 1u)) >> 16;
}
__device__ __forceinline__ void split2(float v, short* h, short* s) {
    unsigned int u  = __float_as_uint(v);
    unsigned int hi = rne16(u);
    float lof = v - __uint_as_float(hi << 16);
    *h = (short)hi;
    *s = (short)rne16(__float_as_uint(lof));
}
// cheaper variant for np_main: RNE hi, truncated lo (error still ~2^-16 rel)
__device__ __forceinline__ void split2t(float v, short* h, short* s) {
    unsigned int u  = __float_as_uint(v);
    unsigned int hi = rne16(u);
    float lof = v - __uint_as_float(hi << 16);
    *h = (short)hi;
    *s = (short)(__float_as_uint(lof) >> 16);
}
// mask frag: half = (a positive ? bf16(1.0) : 0). Exact {0,1} in bf16.
__device__ __forceinline__ bf16x8 maskone(bf16x8 a) {
    union { bf16x8 v; unsigned int u[4]; } A, M;
    A.v = a;
    #pragma unroll
    for (int j = 0; j < 4; ++j) {
        unsigned int t = (~A.u[j]) & 0x80008000u;   // sign==0 (positive) halves
        M.u[j] = (t >> 15) * 0x3F80u;               // per-half 1.0bf16
    }
    return M.v;
}

// ---- fused prep ----
// blocks [0,1026):   x -> XH/XL
// blocks [1026,1410): weight frags; W1 canonical k-order,
//                     W2 AND V (= w1l.*W2) in pi k-order:
//                       h = kc2*32 + (j>>2)*16 + q*4 + (j&3)
// blocks [1410,1474): RSV (parallel, 256 thr) + WLF fp32 w1_last table
__global__ __launch_bounds__(256)
void prep_all(const float* __restrict__ x, const float* __restrict__ W1,
              const float* __restrict__ W2,
              short* __restrict__ XH, short* __restrict__ XL,
              short* __restrict__ W1H, short* __restrict__ W1L,
              short* __restrict__ W2H, short* __restrict__ W2L,
              short* __restrict__ VH,  short* __restrict__ VL,
              float* __restrict__ WLF, float* __restrict__ RSV)
{
    const int b = blockIdx.x, tid = threadIdx.x;
    if (b < 1026) {
        int i = (b * 256 + tid) * 4;
        float4 v = *(const float4*)(x + i);
        float vv[4] = {v.x, v.y, v.z, v.w};
        short hh[4], ll[4];
        #pragma unroll
        for (int j = 0; j < 4; ++j) split2(vv[j], &hh[j], &ll[j]);
        *(short4*)&XH[i] = make_short4(hh[0], hh[1], hh[2], hh[3]);
        *(short4*)&XL[i] = make_short4(ll[0], ll[1], ll[2], ll[3]);
    } else if (b < 1410) {
        int e = (b - 1026) * 256 + tid;          // 0..98303
        int l = e / 1536, r = e - l * 1536;
        if (r < 1024) {                           // W1 frag elem (canonical k-order)
            int fid = r >> 6, lane = r & 63;
            int fk = fid >> 2, nt = fid & 3;
            int h  = nt * 16 + (lane & 15);
            int f0 = fk * 32 + (lane >> 4) * 8;
            const float* src = W1 + (size_t)l * 8256 + h * 129 + f0;
            size_t o = (size_t)l * 8192 + (size_t)r * 8;
            #pragma unroll
            for (int j = 0; j < 8; ++j) {
                short h_, l_; split2(src[j], &h_, &l_);
                W1H[o + j] = h_; W1L[o + j] = l_;
            }
        } else {                                  // W2 + V frag elem in pi k-order
            int r2 = r - 1024;
            int fid = r2 >> 6, lane = r2 & 63;
            int kc2 = fid >> 2, nt = fid & 3;
            int g  = nt * 16 + (lane & 15);
            int qq = lane >> 4;
            const float* src = W2 + (size_t)l * 4096 + g * 64 + kc2 * 32 + qq * 4;
            const float* wlp = W1 + (size_t)l * 8256 + 128;  // wl[h] = wlp[h*129]
            size_t o = (size_t)l * 4096 + (size_t)r2 * 8;
            #pragma unroll
            for (int j = 0; j < 8; ++j) {
                int hoff = ((j >> 2) << 4) + (j & 3);   // jj*16 + rr
                float w2v = src[hoff];
                short h_, l_;
                split2(w2v, &h_, &l_);
                W2H[o + j] = h_; W2L[o + j] = l_;
                int h_abs = kc2 * 32 + qq * 4 + hoff;
                float vv = w2v * wlp[(size_t)h_abs * 129];
                split2(vv, &h_, &l_);
                VH[o + j] = h_; VL[o + j] = l_;
            }
        }
    } else {
        const int l = b - 1410;
        const float* wlp = W1 + (size_t)l * 8256 + 128;
        int g = tid >> 2, part = tid & 3;
        const float* w2row = W2 + (size_t)l * 4096 + g * 64 + part * 16;
        float p = 0.f;
        #pragma unroll 4
        for (int hh = 0; hh < 16; ++hh)
            p += w2row[hh] * wlp[(size_t)(part * 16 + hh) * 129];
        p += __shfl_xor(p, 1);
        p += __shfl_xor(p, 2);
        if (part == 0) RSV[l * 64 + g] = p;
        if (tid < 64) WLF[l * 64 + tid] = wlp[(size_t)tid * 129];
    }
}

// logdet[n] = sum of 8 per-l-part partials
__global__ __launch_bounds__(256)
void finish_logdet(const float* __restrict__ PDP, float* __restrict__ logdet) {
    int i = blockIdx.x * 256 + threadIdx.x;      // grid exact: NTOT/256
    float acc = 0.f;
    #pragma unroll
    for (int p = 0; p < 8; ++p)
        acc += PDP[(size_t)p * NTOT + i];
    logdet[i] = acc;
}

// LDS-free, l-fused main kernel.
//   grid = (NTOT/128 row-tiles, 8 l-parts); wave = 32 rows, loops 8 l's.
//   Stage 1: z1^T = mfma(W1frag, Xfrag) -> lane holds a1[n=c16][h=nt*16+q*4+r]
//   Stage 2 (pi k-order baked into W2/V prep): B-frag dwords == packed (hi,lo)
//     pair dwords from finalize. za = a1@W2' (3-pass), zm = mask@V (2-pass,
//     mask exact {0,1} bf16, V = w1l.*W2 split from fp32 product).
//   log|dJ| accumulated in-register across the l-loop -> PDP partials
//   (kills the 4 MB PD array + its read-back).
__global__ __launch_bounds__(256, 4)
void np_main(const float* __restrict__ x,
             const float* __restrict__ b1, const float* __restrict__ b2,
             const float* __restrict__ W3, const float* __restrict__ b3,
             const short* __restrict__ XH, const short* __restrict__ XL,
             const short* __restrict__ W1H, const short* __restrict__ W1L,
             const short* __restrict__ W2H, const short* __restrict__ W2L,
             const short* __restrict__ VH,  const short* __restrict__ VL,
             const float* __restrict__ WLF, const float* __restrict__ RSV,
             float* __restrict__ PDP, float* __restrict__ out)
{
    const int tid = threadIdx.x;
    const int nb = blockIdx.x * 128;             // row tile
    const int l0 = blockIdx.y * 8;               // l part
    const int bb = nb >> 10, t0 = nb & 1023;
    const int lane = tid & 63, wid = tid >> 6;
    const int q = lane >> 4, c16 = lane & 15;
    const int wrow = wid * 32;                   // wave's 32 rows within block
    const size_t xrow0 = (size_t)(bb * TT + t0);
    const int n = nb + wrow + q * 16 + c16;      // this lane's output row (q<2)

    float acc_log = 0.f;

    #pragma unroll 1
    for (int l = l0; l < l0 + 8; ++l) {
        // x_t + b3 issued early (hidden under stage-1 MFMA)
        float xt[2];
        #pragma unroll
        for (int mt = 0; mt < 2; ++mt)
            xt[mt] = x[(xrow0 + wrow + mt * 16 + c16 + 2) * 64 + l];
        const float b3l = b3[l];

        // ---- stage 1: zT[nt][mt] = W1'@x_lags^T + b1 (seeded), 3-pass ----
        f32x4 zT[4][2];
        #pragma unroll
        for (int nt = 0; nt < 4; ++nt) {
            float4 b1c = *(const float4*)(b1 + l * 64 + nt * 16 + q * 4);
            zT[nt][0] = (f32x4){b1c.x, b1c.y, b1c.z, b1c.w};
            zT[nt][1] = zT[nt][0];
        }
        const short* w1hb = W1H + (size_t)l * 8192;
        const short* w1lb = W1L + (size_t)l * 8192;
        #pragma unroll
        for (int fk = 0; fk < 4; ++fk) {
            const int colx = (fk & 1) * 32 + q * 8;
            const int rofs = fk >> 1;
            bf16x8 xh[2], xl[2], wh[4], wl[4];
            #pragma unroll
            for (int mt = 0; mt < 2; ++mt) {
                size_t xo = (size_t)(xrow0 + wrow + mt * 16 + c16 + rofs) * 64 + colx;
                xh[mt] = *(const bf16x8*)(XH + xo);
                xl[mt] = *(const bf16x8*)(XL + xo);
            }
            #pragma unroll
            for (int nt = 0; nt < 4; ++nt) {
                size_t wo = (size_t)((fk * 4 + nt) * 64 + lane) * 8;
                wh[nt] = *(const bf16x8*)(w1hb + wo);
                wl[nt] = *(const bf16x8*)(w1lb + wo);
            }
            #pragma unroll
            for (int nt = 0; nt < 4; ++nt)
                #pragma unroll
                for (int mt = 0; mt < 2; ++mt) {
                    zT[nt][mt] = __builtin_amdgcn_mfma_f32_16x16x32_bf16(wh[nt], xh[mt], zT[nt][mt], 0, 0, 0);
                    zT[nt][mt] = __builtin_amdgcn_mfma_f32_16x16x32_bf16(wh[nt], xl[mt], zT[nt][mt], 0, 0, 0);
                    zT[nt][mt] = __builtin_amdgcn_mfma_f32_16x16x32_bf16(wl[nt], xh[mt], zT[nt][mt], 0, 0, 0);
                }
        }

        // ---- per-mt: finalize -> stage 2 -> epilogue ----
        union U { bf16x8 v; unsigned u[4]; };
        const short* w2hb = W2H + (size_t)l * 4096;
        const short* w2lb = W2L + (size_t)l * 4096;
        const short* vhb  = VH  + (size_t)l * 4096;
        const short* vlb  = VL  + (size_t)l * 4096;
        float po_keep = 0.f, pd_keep = 0.f;

        #pragma unroll
        for (int mt = 0; mt < 2; ++mt) {
            // finalize: a1 = leaky(zT + xt*w1_last) -> pk frag dwords
            unsigned pkh[4][2], pkl[4][2];
            #pragma unroll
            for (int nt = 0; nt < 4; ++nt) {
                float4 wc = *(const float4*)(WLF + l * 64 + nt * 16 + q * 4);
                float w1c[4] = {wc.x, wc.y, wc.z, wc.w};
                #pragma unroll
                for (int p = 0; p < 2; ++p) {
                    float v0 = zT[nt][mt][2*p]   + xt[mt] * w1c[2*p];
                    float v1 = zT[nt][mt][2*p+1] + xt[mt] * w1c[2*p+1];
                    float a0  = fmaxf(v0, 0.01f * v0);
                    float a1v = fmaxf(v1, 0.01f * v1);
                    short h0, s0, h1, s1;
                    split2t(a0,  &h0, &s0);
                    split2t(a1v, &h1, &s1);
                    pkh[nt][p] = (unsigned)(unsigned short)h0 | ((unsigned)(unsigned short)h1 << 16);
                    pkl[nt][p] = (unsigned)(unsigned short)s0 | ((unsigned)(unsigned short)s1 << 16);
                }
            }

            // stage 2: za = a1@W2' + b2 (seeded, 3-pass), zm = mask@V (2-pass)
            f32x4 za[4], zm[4];
            #pragma unroll
            for (int gt = 0; gt < 4; ++gt) {
                float4 b2c = *(const float4*)(b2 + l * 64 + gt * 16 + q * 4);
                za[gt] = (f32x4){b2c.x, b2c.y, b2c.z, b2c.w};
                zm[gt] = (f32x4){0.f, 0.f, 0.f, 0.f};
            }
            #pragma unroll
            for (int kc2 = 0; kc2 < 2; ++kc2) {
                U ah, al;
                ah.u[0] = pkh[2*kc2  ][0]; ah.u[1] = pkh[2*kc2  ][1];
                ah.u[2] = pkh[2*kc2+1][0]; ah.u[3] = pkh[2*kc2+1][1];
                al.u[0] = pkl[2*kc2  ][0]; al.u[1] = pkl[2*kc2  ][1];
                al.u[2] = pkl[2*kc2+1][0]; al.u[3] = pkl[2*kc2+1][1];
                bf16x8 mk = maskone(ah.v);
                #pragma unroll
                for (int gt = 0; gt < 4; ++gt) {
                    size_t wo = (size_t)((kc2 * 4 + gt) * 64 + lane) * 8;
                    bf16x8 w2h = *(const bf16x8*)(w2hb + wo);
                    bf16x8 w2l = *(const bf16x8*)(w2lb + wo);
                    bf16x8 vh  = *(const bf16x8*)(vhb + wo);
                    bf16x8 vl  = *(const bf16x8*)(vlb + wo);
                    za[gt] = __builtin_amdgcn_mfma_f32_16x16x32_bf16(w2h, ah.v, za[gt], 0, 0, 0);
                    za[gt] = __builtin_amdgcn_mfma_f32_16x16x32_bf16(w2h, al.v, za[gt], 0, 0, 0);
                    za[gt] = __builtin_amdgcn_mfma_f32_16x16x32_bf16(w2l, ah.v, za[gt], 0, 0, 0);
                    zm[gt] = __builtin_amdgcn_mfma_f32_16x16x32_bf16(vh,  mk,   zm[gt], 0, 0, 0);
                    zm[gt] = __builtin_amdgcn_mfma_f32_16x16x32_bf16(vl,  mk,   zm[gt], 0, 0, 0);
                }
            }

            // epilogue: g = gt*16 + q*4 + r is lane-local (b2 already in za)
            float po = 0.f, pd = 0.f;
            #pragma unroll
            for (int gt = 0; gt < 4; ++gt) {
                float4 w3c = *(const float4*)(W3 + l * 64 + gt * 16 + q * 4);
                float4 rc  = *(const float4*)(RSV + l * 64 + gt * 16 + q * 4);
                float w3a[4] = {w3c.x, w3c.y, w3c.z, w3c.w};
                float rca[4] = {rc.x,  rc.y,  rc.z,  rc.w};
                #pragma unroll
                for (int r = 0; r < 4; ++r) {
                    float zv = za[gt][r];
                    float a2 = fmaxf(zv, 0.01f * zv);
                    float zt = 0.99f * zm[gt][r] + 0.01f * rca[r];
                    po += a2 * w3a[r];
                    pd += (zv > 0.f ? w3a[r] : 0.01f * w3a[r]) * zt;
                }
            }
            po += __shfl_xor(po, 16);
            po += __shfl_xor(po, 32);
            pd += __shfl_xor(pd, 16);
            pd += __shfl_xor(pd, 32);
            if (q == mt) { po_keep = po; pd_keep = pd; }
        }

        if (q < 2) out[(size_t)n * 64 + l] = po_keep + b3l;
        acc_log += __logf(fabsf(pd_keep));   // q>=2 lanes: -inf, never stored
    }

    if (q < 2) PDP[(size_t)blockIdx.y * NTOT + n] = acc_log;
}

extern "C" void kernel_launch(void* const* d_in, const int* in_sizes, int n_in,
                              void* d_out, int out_size, void* d_ws, size_t ws_size,
                              hipStream_t stream) {
    const float* x  = (const float*)d_in[0];
    const float* W1 = (const float*)d_in[1];
    const float* b1 = (const float*)d_in[2];
    const float* W2 = (const float*)d_in[3];
    const float* b2 = (const float*)d_in[4];
    const float* W3 = (const float*)d_in[5];
    const float* b3 = (const float*)d_in[6];
    float* out = (float*)d_out;
    char* ws = (char*)d_ws;

    short* XH   = (short*)(ws + OXH);
    short* XL   = (short*)(ws + OXL);
    short* W1Hp = (short*)(ws + OW1H);
    short* W1Lp = (short*)(ws + OW1L);
    short* W2Hp = (short*)(ws + OW2H);
    short* W2Lp = (short*)(ws + OW2L);
    short* VHp  = (short*)(ws + OVH);
    short* VLp  = (short*)(ws + OVL);
    float* WLFp = (float*)(ws + OWLF);
    float* RSVp = (float*)(ws + ORSV);
    float* PDPp = (float*)(ws + OPDP);

    hipLaunchKernelGGL(prep_all, dim3(1026 + 384 + 64), dim3(256), 0, stream,
                       x, W1, W2, XH, XL, W1Hp, W1Lp, W2Hp, W2Lp, VHp, VLp,
                       WLFp, RSVp);
    dim3 grid(NTOT / 128 /*row tiles*/, 8 /*l parts*/);
    hipLaunchKernelGGL(np_main, grid, dim3(256), 0, stream,
                       x, b1, b2, W3, b3,
                       XH, XL, W1Hp, W1Lp, W2Hp, W2Lp, VHp, VLp,
                       WLFp, RSVp, PDPp, out);
    hipLaunchKernelGGL(finish_logdet, dim3(NTOT / 256), dim3(256), 0, stream,
                       PDPp, out + (size_t)NTOT * 64);
}

// Round 6
// 419.841 us; speedup vs baseline: 1.0252x; 1.0252x over previous
//
#include <hip/hip_runtime.h>
#include <math.h>

#define BB   16
#define TT   1026
#define LEN  1024
#define NTOT (BB*LEN)        // 16384
#define NX   (BB*TT*64)      // 1050624 floats in x

typedef __attribute__((ext_vector_type(8))) short bf16x8;
typedef __attribute__((ext_vector_type(4))) float f32x4;

// ---- ws byte offsets ----
#define OXH   ((size_t)0)                     // XH: NX shorts
#define OXL   (OXH + (size_t)NX*2)            // XL: NX shorts
#define OW1H  (OXL + (size_t)NX*2)            // 64 l * 8192 shorts
#define OW1L  (OW1H + (size_t)64*8192*2)
#define OW2H  (OW1L + (size_t)64*8192*2)      // 64 l * 4096 shorts (pi k-order)
#define OW2L  (OW2H + (size_t)64*4096*2)
#define OVH   (OW2L + (size_t)64*4096*2)      // V = w1l .* W2, hi split (pi k-order)
#define OVL   (OVH + (size_t)64*4096*2)
#define OWLF  (OVL + (size_t)64*4096*2)       // f32 [64][64] w1_last transposed
#define ORSV  (OWLF + (size_t)64*64*4)        // f32 [64*64]
#define OPDP  (ORSV + (size_t)64*64*4)        // f32 [8][16384] logdet partials

__device__ __forceinline__ unsigned int rne16(unsigned int u) {
    return (u + 0x7FFFu + ((u >> 16) & 1u)) >> 16;
}
__device__ __forceinline__ void split2(float v, short* h, short* s) {
    unsigned int u  = __float_as_uint(v);
    unsigned int hi = rne16(u);
    float lof = v - __uint_as_float(hi << 16);
    *h = (short)hi;
    *s = (short)rne16(__float_as_uint(lof));
}
// cheaper variant for np_main: RNE hi, truncated lo (error still ~2^-16 rel)
__device__ __forceinline__ void split2t(float v, short* h, short* s) {
    unsigned int u  = __float_as_uint(v);
    unsigned int hi = rne16(u);
    float lof = v - __uint_as_float(hi << 16);
    *h = (short)hi;
    *s = (short)(__float_as_uint(lof) >> 16);
}
// mask frag: half = (a positive ? bf16(1.0) : 0). Exact {0,1} in bf16.
__device__ __forceinline__ bf16x8 maskone(bf16x8 a) {
    union { bf16x8 v; unsigned int u[4]; } A, M;
    A.v = a;
    #pragma unroll
    for (int j = 0; j < 4; ++j) {
        unsigned int t = (~A.u[j]) & 0x80008000u;   // sign==0 (positive) halves
        M.u[j] = (t >> 15) * 0x3F80u;               // per-half 1.0bf16
    }
    return M.v;
}

// ---- fused prep ----
// blocks [0,1026):   x -> XH/XL
// blocks [1026,1410): weight frags; W1 canonical k-order,
//                     W2 AND V (= w1l.*W2) in pi k-order:
//                       h = kc2*32 + (j>>2)*16 + q*4 + (j&3)
// blocks [1410,1474): RSV (parallel, 256 thr) + WLF fp32 w1_last table
__global__ __launch_bounds__(256)
void prep_all(const float* __restrict__ x, const float* __restrict__ W1,
              const float* __restrict__ W2,
              short* __restrict__ XH, short* __restrict__ XL,
              short* __restrict__ W1H, short* __restrict__ W1L,
              short* __restrict__ W2H, short* __restrict__ W2L,
              short* __restrict__ VH,  short* __restrict__ VL,
              float* __restrict__ WLF, float* __restrict__ RSV)
{
    const int b = blockIdx.x, tid = threadIdx.x;
    if (b < 1026) {
        int i = (b * 256 + tid) * 4;
        float4 v = *(const float4*)(x + i);
        float vv[4] = {v.x, v.y, v.z, v.w};
        short hh[4], ll[4];
        #pragma unroll
        for (int j = 0; j < 4; ++j) split2(vv[j], &hh[j], &ll[j]);
        *(short4*)&XH[i] = make_short4(hh[0], hh[1], hh[2], hh[3]);
        *(short4*)&XL[i] = make_short4(ll[0], ll[1], ll[2], ll[3]);
    } else if (b < 1410) {
        int e = (b - 1026) * 256 + tid;          // 0..98303
        int l = e / 1536, r = e - l * 1536;
        if (r < 1024) {                           // W1 frag elem (canonical k-order)
            int fid = r >> 6, lane = r & 63;
            int fk = fid >> 2, nt = fid & 3;
            int h  = nt * 16 + (lane & 15);
            int f0 = fk * 32 + (lane >> 4) * 8;
            const float* src = W1 + (size_t)l * 8256 + h * 129 + f0;
            size_t o = (size_t)l * 8192 + (size_t)r * 8;
            #pragma unroll
            for (int j = 0; j < 8; ++j) {
                short h_, l_; split2(src[j], &h_, &l_);
                W1H[o + j] = h_; W1L[o + j] = l_;
            }
        } else {                                  // W2 + V frag elem in pi k-order
            int r2 = r - 1024;
            int fid = r2 >> 6, lane = r2 & 63;
            int kc2 = fid >> 2, nt = fid & 3;
            int g  = nt * 16 + (lane & 15);
            int qq = lane >> 4;
            const float* src = W2 + (size_t)l * 4096 + g * 64 + kc2 * 32 + qq * 4;
            const float* wlp = W1 + (size_t)l * 8256 + 128;  // wl[h] = wlp[h*129]
            size_t o = (size_t)l * 4096 + (size_t)r2 * 8;
            #pragma unroll
            for (int j = 0; j < 8; ++j) {
                int hoff = ((j >> 2) << 4) + (j & 3);   // jj*16 + rr
                float w2v = src[hoff];
                short h_, l_;
                split2(w2v, &h_, &l_);
                W2H[o + j] = h_; W2L[o + j] = l_;
                int h_abs = kc2 * 32 + qq * 4 + hoff;
                float vv = w2v * wlp[(size_t)h_abs * 129];
                split2(vv, &h_, &l_);
                VH[o + j] = h_; VL[o + j] = l_;
            }
        }
    } else {
        const int l = b - 1410;
        const float* wlp = W1 + (size_t)l * 8256 + 128;
        int g = tid >> 2, part = tid & 3;
        const float* w2row = W2 + (size_t)l * 4096 + g * 64 + part * 16;
        float p = 0.f;
        #pragma unroll 4
        for (int hh = 0; hh < 16; ++hh)
            p += w2row[hh] * wlp[(size_t)(part * 16 + hh) * 129];
        p += __shfl_xor(p, 1);
        p += __shfl_xor(p, 2);
        if (part == 0) RSV[l * 64 + g] = p;
        if (tid < 64) WLF[l * 64 + tid] = wlp[(size_t)tid * 129];
    }
}

// logdet[n] = sum of 8 per-l-part partials
__global__ __launch_bounds__(256)
void finish_logdet(const float* __restrict__ PDP, float* __restrict__ logdet) {
    int i = blockIdx.x * 256 + threadIdx.x;      // grid exact: NTOT/256
    float acc = 0.f;
    #pragma unroll
    for (int p = 0; p < 8; ++p)
        acc += PDP[(size_t)p * NTOT + i];
    logdet[i] = acc;
}

// LDS-free, l-fused main kernel.
//   grid = (NTOT/128 row-tiles, 8 l-parts); wave = 32 rows, loops 8 l's.
//   Stage 1: z1^T = mfma(W1frag, Xfrag) -> lane holds a1[n=c16][h=nt*16+q*4+r]
//   Stage 2 (pi k-order baked into W2/V prep): B-frag dwords == packed (hi,lo)
//     pair dwords from finalize. za = a1@W2' (3-pass), zm = mask@V (2-pass,
//     mask exact {0,1} bf16, V = w1l.*W2 split from fp32 product).
//   log|dJ| accumulated in-register across the l-loop -> PDP partials.
// OCCUPANCY NOTE: (256,3) is the proven no-spill point (r4: VGPR 76, clean
// WRITE_SIZE). (256,4) caps unified VGPR+AGPR at 128 -> catastrophic scratch
// spill (r5: 462 MB WRITE_SIZE, 3.4x slower). Do not raise without shrinking
// per-wave state.
__global__ __launch_bounds__(256, 3)
void np_main(const float* __restrict__ x,
             const float* __restrict__ b1, const float* __restrict__ b2,
             const float* __restrict__ W3, const float* __restrict__ b3,
             const short* __restrict__ XH, const short* __restrict__ XL,
             const short* __restrict__ W1H, const short* __restrict__ W1L,
             const short* __restrict__ W2H, const short* __restrict__ W2L,
             const short* __restrict__ VH,  const short* __restrict__ VL,
             const float* __restrict__ WLF, const float* __restrict__ RSV,
             float* __restrict__ PDP, float* __restrict__ out)
{
    const int tid = threadIdx.x;
    const int nb = blockIdx.x * 128;             // row tile
    const int l0 = blockIdx.y * 8;               // l part
    const int bb = nb >> 10, t0 = nb & 1023;
    const int lane = tid & 63, wid = tid >> 6;
    const int q = lane >> 4, c16 = lane & 15;
    const int wrow = wid * 32;                   // wave's 32 rows within block
    const size_t xrow0 = (size_t)(bb * TT + t0);
    const int n = nb + wrow + q * 16 + c16;      // this lane's output row (q<2)

    float acc_log = 0.f;

    #pragma unroll 1
    for (int l = l0; l < l0 + 8; ++l) {
        // x_t + b3 issued early (hidden under stage-1 MFMA)
        float xt[2];
        #pragma unroll
        for (int mt = 0; mt < 2; ++mt)
            xt[mt] = x[(xrow0 + wrow + mt * 16 + c16 + 2) * 64 + l];
        const float b3l = b3[l];

        // ---- stage 1: zT[nt][mt] = W1'@x_lags^T + b1 (seeded), 3-pass ----
        f32x4 zT[4][2];
        #pragma unroll
        for (int nt = 0; nt < 4; ++nt) {
            float4 b1c = *(const float4*)(b1 + l * 64 + nt * 16 + q * 4);
            zT[nt][0] = (f32x4){b1c.x, b1c.y, b1c.z, b1c.w};
            zT[nt][1] = zT[nt][0];
        }
        const short* w1hb = W1H + (size_t)l * 8192;
        const short* w1lb = W1L + (size_t)l * 8192;
        #pragma unroll
        for (int fk = 0; fk < 4; ++fk) {
            const int colx = (fk & 1) * 32 + q * 8;
            const int rofs = fk >> 1;
            bf16x8 xh[2], xl[2], wh[4], wl[4];
            #pragma unroll
            for (int mt = 0; mt < 2; ++mt) {
                size_t xo = (size_t)(xrow0 + wrow + mt * 16 + c16 + rofs) * 64 + colx;
                xh[mt] = *(const bf16x8*)(XH + xo);
                xl[mt] = *(const bf16x8*)(XL + xo);
            }
            #pragma unroll
            for (int nt = 0; nt < 4; ++nt) {
                size_t wo = (size_t)((fk * 4 + nt) * 64 + lane) * 8;
                wh[nt] = *(const bf16x8*)(w1hb + wo);
                wl[nt] = *(const bf16x8*)(w1lb + wo);
            }
            #pragma unroll
            for (int nt = 0; nt < 4; ++nt)
                #pragma unroll
                for (int mt = 0; mt < 2; ++mt) {
                    zT[nt][mt] = __builtin_amdgcn_mfma_f32_16x16x32_bf16(wh[nt], xh[mt], zT[nt][mt], 0, 0, 0);
                    zT[nt][mt] = __builtin_amdgcn_mfma_f32_16x16x32_bf16(wh[nt], xl[mt], zT[nt][mt], 0, 0, 0);
                    zT[nt][mt] = __builtin_amdgcn_mfma_f32_16x16x32_bf16(wl[nt], xh[mt], zT[nt][mt], 0, 0, 0);
                }
        }

        // ---- per-mt: finalize -> stage 2 -> epilogue ----
        union U { bf16x8 v; unsigned u[4]; };
        const short* w2hb = W2H + (size_t)l * 4096;
        const short* w2lb = W2L + (size_t)l * 4096;
        const short* vhb  = VH  + (size_t)l * 4096;
        const short* vlb  = VL  + (size_t)l * 4096;
        float po_keep = 0.f, pd_keep = 0.f;

        #pragma unroll
        for (int mt = 0; mt < 2; ++mt) {
            // finalize: a1 = leaky(zT + xt*w1_last) -> pk frag dwords
            unsigned pkh[4][2], pkl[4][2];
            #pragma unroll
            for (int nt = 0; nt < 4; ++nt) {
                float4 wc = *(const float4*)(WLF + l * 64 + nt * 16 + q * 4);
                float w1c[4] = {wc.x, wc.y, wc.z, wc.w};
                #pragma unroll
                for (int p = 0; p < 2; ++p) {
                    float v0 = zT[nt][mt][2*p]   + xt[mt] * w1c[2*p];
                    float v1 = zT[nt][mt][2*p+1] + xt[mt] * w1c[2*p+1];
                    float a0  = fmaxf(v0, 0.01f * v0);
                    float a1v = fmaxf(v1, 0.01f * v1);
                    short h0, s0, h1, s1;
                    split2t(a0,  &h0, &s0);
                    split2t(a1v, &h1, &s1);
                    pkh[nt][p] = (unsigned)(unsigned short)h0 | ((unsigned)(unsigned short)h1 << 16);
                    pkl[nt][p] = (unsigned)(unsigned short)s0 | ((unsigned)(unsigned short)s1 << 16);
                }
            }

            // stage 2: za = a1@W2' + b2 (seeded, 3-pass), zm = mask@V (2-pass)
            f32x4 za[4], zm[4];
            #pragma unroll
            for (int gt = 0; gt < 4; ++gt) {
                float4 b2c = *(const float4*)(b2 + l * 64 + gt * 16 + q * 4);
                za[gt] = (f32x4){b2c.x, b2c.y, b2c.z, b2c.w};
                zm[gt] = (f32x4){0.f, 0.f, 0.f, 0.f};
            }
            #pragma unroll
            for (int kc2 = 0; kc2 < 2; ++kc2) {
                U ah, al;
                ah.u[0] = pkh[2*kc2  ][0]; ah.u[1] = pkh[2*kc2  ][1];
                ah.u[2] = pkh[2*kc2+1][0]; ah.u[3] = pkh[2*kc2+1][1];
                al.u[0] = pkl[2*kc2  ][0]; al.u[1] = pkl[2*kc2  ][1];
                al.u[2] = pkl[2*kc2+1][0]; al.u[3] = pkl[2*kc2+1][1];
                bf16x8 mk = maskone(ah.v);
                #pragma unroll
                for (int gt = 0; gt < 4; ++gt) {
                    size_t wo = (size_t)((kc2 * 4 + gt) * 64 + lane) * 8;
                    bf16x8 w2h = *(const bf16x8*)(w2hb + wo);
                    bf16x8 w2l = *(const bf16x8*)(w2lb + wo);
                    bf16x8 vh  = *(const bf16x8*)(vhb + wo);
                    bf16x8 vl  = *(const bf16x8*)(vlb + wo);
                    za[gt] = __builtin_amdgcn_mfma_f32_16x16x32_bf16(w2h, ah.v, za[gt], 0, 0, 0);
                    za[gt] = __builtin_amdgcn_mfma_f32_16x16x32_bf16(w2h, al.v, za[gt], 0, 0, 0);
                    za[gt] = __builtin_amdgcn_mfma_f32_16x16x32_bf16(w2l, ah.v, za[gt], 0, 0, 0);
                    zm[gt] = __builtin_amdgcn_mfma_f32_16x16x32_bf16(vh,  mk,   zm[gt], 0, 0, 0);
                    zm[gt] = __builtin_amdgcn_mfma_f32_16x16x32_bf16(vl,  mk,   zm[gt], 0, 0, 0);
                }
            }

            // epilogue: g = gt*16 + q*4 + r is lane-local (b2 already in za)
            float po = 0.f, pd = 0.f;
            #pragma unroll
            for (int gt = 0; gt < 4; ++gt) {
                float4 w3c = *(const float4*)(W3 + l * 64 + gt * 16 + q * 4);
                float4 rc  = *(const float4*)(RSV + l * 64 + gt * 16 + q * 4);
                float w3a[4] = {w3c.x, w3c.y, w3c.z, w3c.w};
                float rca[4] = {rc.x,  rc.y,  rc.z,  rc.w};
                #pragma unroll
                for (int r = 0; r < 4; ++r) {
                    float zv = za[gt][r];
                    float a2 = fmaxf(zv, 0.01f * zv);
                    float zt = 0.99f * zm[gt][r] + 0.01f * rca[r];
                    po += a2 * w3a[r];
                    pd += (zv > 0.f ? w3a[r] : 0.01f * w3a[r]) * zt;
                }
            }
            po += __shfl_xor(po, 16);
            po += __shfl_xor(po, 32);
            pd += __shfl_xor(pd, 16);
            pd += __shfl_xor(pd, 32);
            if (q == mt) { po_keep = po; pd_keep = pd; }
        }

        if (q < 2) out[(size_t)n * 64 + l] = po_keep + b3l;
        acc_log += __logf(fabsf(pd_keep));   // q>=2 lanes: -inf, never stored
    }

    if (q < 2) PDP[(size_t)blockIdx.y * NTOT + n] = acc_log;
}

extern "C" void kernel_launch(void* const* d_in, const int* in_sizes, int n_in,
                              void* d_out, int out_size, void* d_ws, size_t ws_size,
                              hipStream_t stream) {
    const float* x  = (const float*)d_in[0];
    const float* W1 = (const float*)d_in[1];
    const float* b1 = (const float*)d_in[2];
    const float* W2 = (const float*)d_in[3];
    const float* b2 = (const float*)d_in[4];
    const float* W3 = (const float*)d_in[5];
    const float* b3 = (const float*)d_in[6];
    float* out = (float*)d_out;
    char* ws = (char*)d_ws;

    short* XH   = (short*)(ws + OXH);
    short* XL   = (short*)(ws + OXL);
    short* W1Hp = (short*)(ws + OW1H);
    short* W1Lp = (short*)(ws + OW1L);
    short* W2Hp = (short*)(ws + OW2H);
    short* W2Lp = (short*)(ws + OW2L);
    short* VHp  = (short*)(ws + OVH);
    short* VLp  = (short*)(ws + OVL);
    float* WLFp = (float*)(ws + OWLF);
    float* RSVp = (float*)(ws + ORSV);
    float* PDPp = (float*)(ws + OPDP);

    hipLaunchKernelGGL(prep_all, dim3(1026 + 384 + 64), dim3(256), 0, stream,
                       x, W1, W2, XH, XL, W1Hp, W1Lp, W2Hp, W2Lp, VHp, VLp,
                       WLFp, RSVp);
    dim3 grid(NTOT / 128 /*row tiles*/, 8 /*l parts*/);
    hipLaunchKernelGGL(np_main, grid, dim3(256), 0, stream,
                       x, b1, b2, W3, b3,
                       XH, XL, W1Hp, W1Lp, W2Hp, W2Lp, VHp, VLp,
                       WLFp, RSVp, PDPp, out);
    hipLaunchKernelGGL(finish_logdet, dim3(NTOT / 256), dim3(256), 0, stream,
                       PDPp, out + (size_t)NTOT * 64);
}

// Round 7
// 231.633 us; speedup vs baseline: 1.8581x; 1.8125x over previous
//
#include <hip/hip_runtime.h>
#include <hip/hip_bf16.h>
#include <math.h>

#define BB   16
#define TT   1026
#define LEN  1024
#define NTOT (BB*LEN)        // 16384
#define NX   (BB*TT*64)      // 1050624 floats in x

typedef __attribute__((ext_vector_type(8))) short bf16x8;
typedef __attribute__((ext_vector_type(4))) float f32x4;

// ---- ws byte offsets ----
#define OXH   ((size_t)0)                     // XH: NX shorts
#define OXL   (OXH + (size_t)NX*2)            // XL: NX shorts
#define OW1H  (OXL + (size_t)NX*2)            // 64 l * 8192 shorts
#define OW1L  (OW1H + (size_t)64*8192*2)
#define OW2H  (OW1L + (size_t)64*8192*2)      // 64 l * 4096 shorts (pi k-order)
#define OW2L  (OW2H + (size_t)64*4096*2)
#define OVH   (OW2L + (size_t)64*4096*2)      // V = w1l .* W2 (pi k-order)
#define OVL   (OVH + (size_t)64*4096*2)
#define OWLF  (OVL + (size_t)64*4096*2)       // f32 [64][64] w1_last transposed
#define ORSV  (OWLF + (size_t)64*64*4)        // f32 [64*64]
#define OPD   (ORSV + (size_t)64*64*4)        // f32 [64][16384] dJ per l,n

__device__ __forceinline__ unsigned int rne16(unsigned int u) {
    return (u + 0x7FFFu + ((u >> 16) & 1u)) >> 16;
}
__device__ __forceinline__ void split2(float v, short* h, short* s) {
    unsigned int u  = __float_as_uint(v);
    unsigned int hi = rne16(u);
    float lof = v - __uint_as_float(hi << 16);
    *h = (short)hi;
    *s = (short)rne16(__float_as_uint(lof));
}
// packed finalize: hi = RNE bf16 pair via HW cvt (numerics == split2t hi),
// lo = truncated residual pair. Returns (hp, lp) dwords, low16 = first value.
__device__ __forceinline__ void pack2(float v0, float v1, unsigned* hp, unsigned* lp) {
    union { __hip_bfloat162 b; unsigned u; } cv;
    cv.b = __float22bfloat162_rn(float2{v0, v1});
    unsigned h = cv.u;
    float f0 = __uint_as_float(h << 16);
    float f1 = __uint_as_float(h & 0xFFFF0000u);
    *hp = h;
    *lp = (__float_as_uint(v0 - f0) >> 16) | (__float_as_uint(v1 - f1) & 0xFFFF0000u);
}
// mask frag: half = (a positive ? bf16(1.0) : 0). Exact {0,1} in bf16.
__device__ __forceinline__ bf16x8 maskone(bf16x8 a) {
    union { bf16x8 v; unsigned int u[4]; } A, M;
    A.v = a;
    #pragma unroll
    for (int j = 0; j < 4; ++j) {
        unsigned int t = (~A.u[j]) & 0x80008000u;   // sign==0 (positive) halves
        M.u[j] = (t >> 15) * 0x3F80u;               // per-half 1.0bf16
    }
    return M.v;
}

// ---- fused prep ----
// blocks [0,1026):   x -> XH/XL
// blocks [1026,1410): weight frags; W1 canonical k-order,
//                     W2 AND V (= w1l.*W2) in pi k-order:
//                       h = kc2*32 + (j>>2)*16 + q*4 + (j&3)
// blocks [1410,1474): RSV (parallel, 256 thr) + WLF fp32 w1_last table
__global__ __launch_bounds__(256)
void prep_all(const float* __restrict__ x, const float* __restrict__ W1,
              const float* __restrict__ W2,
              short* __restrict__ XH, short* __restrict__ XL,
              short* __restrict__ W1H, short* __restrict__ W1L,
              short* __restrict__ W2H, short* __restrict__ W2L,
              short* __restrict__ VH,  short* __restrict__ VL,
              float* __restrict__ WLF, float* __restrict__ RSV)
{
    const int b = blockIdx.x, tid = threadIdx.x;
    if (b < 1026) {
        int i = (b * 256 + tid) * 4;
        float4 v = *(const float4*)(x + i);
        float vv[4] = {v.x, v.y, v.z, v.w};
        short hh[4], ll[4];
        #pragma unroll
        for (int j = 0; j < 4; ++j) split2(vv[j], &hh[j], &ll[j]);
        *(short4*)&XH[i] = make_short4(hh[0], hh[1], hh[2], hh[3]);
        *(short4*)&XL[i] = make_short4(ll[0], ll[1], ll[2], ll[3]);
    } else if (b < 1410) {
        int e = (b - 1026) * 256 + tid;          // 0..98303
        int l = e / 1536, r = e - l * 1536;
        if (r < 1024) {                           // W1 frag elem (canonical k-order)
            int fid = r >> 6, lane = r & 63;
            int fk = fid >> 2, nt = fid & 3;
            int h  = nt * 16 + (lane & 15);
            int f0 = fk * 32 + (lane >> 4) * 8;
            const float* src = W1 + (size_t)l * 8256 + h * 129 + f0;
            size_t o = (size_t)l * 8192 + (size_t)r * 8;
            #pragma unroll
            for (int j = 0; j < 8; ++j) {
                short h_, l_; split2(src[j], &h_, &l_);
                W1H[o + j] = h_; W1L[o + j] = l_;
            }
        } else {                                  // W2 + V frag elem in pi k-order
            int r2 = r - 1024;
            int fid = r2 >> 6, lane = r2 & 63;
            int kc2 = fid >> 2, nt = fid & 3;
            int g  = nt * 16 + (lane & 15);
            int qq = lane >> 4;
            const float* src = W2 + (size_t)l * 4096 + g * 64 + kc2 * 32 + qq * 4;
            const float* wlp = W1 + (size_t)l * 8256 + 128;  // wl[h] = wlp[h*129]
            size_t o = (size_t)l * 4096 + (size_t)r2 * 8;
            #pragma unroll
            for (int j = 0; j < 8; ++j) {
                int hoff = ((j >> 2) << 4) + (j & 3);   // jj*16 + rr
                float w2v = src[hoff];
                short h_, l_;
                split2(w2v, &h_, &l_);
                W2H[o + j] = h_; W2L[o + j] = l_;
                int h_abs = kc2 * 32 + qq * 4 + hoff;
                float vv = w2v * wlp[(size_t)h_abs * 129];
                split2(vv, &h_, &l_);
                VH[o + j] = h_; VL[o + j] = l_;
            }
        }
    } else {
        const int l = b - 1410;
        const float* wlp = W1 + (size_t)l * 8256 + 128;
        int g = tid >> 2, part = tid & 3;
        const float* w2row = W2 + (size_t)l * 4096 + g * 64 + part * 16;
        float p = 0.f;
        #pragma unroll 4
        for (int hh = 0; hh < 16; ++hh)
            p += w2row[hh] * wlp[(size_t)(part * 16 + hh) * 129];
        p += __shfl_xor(p, 1);
        p += __shfl_xor(p, 2);
        if (part == 0) RSV[l * 64 + g] = p;
        if (tid < 64) WLF[l * 64 + tid] = wlp[(size_t)tid * 129];
    }
}

// logdet[n] = sum_l log|PD[l][n]|
__global__ __launch_bounds__(256)
void finish_logdet(const float* __restrict__ PD, float* __restrict__ logdet) {
    int i = blockIdx.x * 256 + threadIdx.x;      // grid exact: NTOT/256
    float acc = 0.f;
    #pragma unroll 8
    for (int l = 0; l < 64; ++l)
        acc += __logf(fabsf(PD[(size_t)l * NTOT + i]));
    logdet[i] = acc;
}

// LDS-free main kernel, 64-row tile: operand-swapped MFMAs keep the whole
// pipeline lane-local. Per-mt finalize (proven anti-spill, r4) at a 256-reg
// budget so the compiler can software-pipeline the weight/x loads itself
// (NO scheduling clobbers — r3 showed they serialize the mt loop).
//   Stage 1: z1^T = mfma(W1frag, Xfrag) -> lane holds a1[n=c16][h=nt*16+q*4+r]
//   Stage 2 (pi k-order baked into W2/V prep): B-frag dwords == packed (hi,lo)
//     pair dwords from finalize. za = a1@W2' + b2 (3-pass), zm = mask@V
//     (2-pass, mask exact {0,1} bf16, V = w1l.*W2 split from fp32 product).
// HISTORY: 32-row @(256,3) = 169us (r4); (256,4) or l-fused loop = scratch
// spill catastrophe (r5/r6, WRITE_SIZE 310-460 MB). Tripwire: WRITE>60MB.
__global__ __launch_bounds__(256, 2)
void np_main(const float* __restrict__ x,
             const float* __restrict__ b1, const float* __restrict__ b2,
             const float* __restrict__ W3, const float* __restrict__ b3,
             const short* __restrict__ XH, const short* __restrict__ XL,
             const short* __restrict__ W1H, const short* __restrict__ W1L,
             const short* __restrict__ W2H, const short* __restrict__ W2L,
             const short* __restrict__ VH,  const short* __restrict__ VL,
             const float* __restrict__ WLF, const float* __restrict__ RSV,
             float* __restrict__ PD, float* __restrict__ out)
{
    const int l = blockIdx.x, tid = threadIdx.x;
    const int nb = blockIdx.y * 256;
    const int bb = nb >> 10, t0 = nb & 1023;
    const int lane = tid & 63, wid = tid >> 6;
    const int q = lane >> 4, c16 = lane & 15;
    const int wrow = wid * 64;                   // wave's 64 rows within block
    const size_t xrow0 = (size_t)(bb * TT + t0);

    // x_t loads issued early (hidden under stage-1 MFMA)
    float xt[4];
    #pragma unroll
    for (int mt = 0; mt < 4; ++mt)
        xt[mt] = x[(xrow0 + wrow + mt * 16 + c16 + 2) * 64 + l];

    // ---- stage 1: zT[nt][mt] = W1'@x_lags^T + b1 (seeded), 3-pass ----
    f32x4 zT[4][4];
    #pragma unroll
    for (int nt = 0; nt < 4; ++nt) {
        float4 b1c = *(const float4*)(b1 + l * 64 + nt * 16 + q * 4);
        zT[nt][0] = (f32x4){b1c.x, b1c.y, b1c.z, b1c.w};
        zT[nt][1] = zT[nt][0];
        zT[nt][2] = zT[nt][0];
        zT[nt][3] = zT[nt][0];
    }
    const short* w1hb = W1H + (size_t)l * 8192;
    const short* w1lb = W1L + (size_t)l * 8192;
    #pragma unroll
    for (int fk = 0; fk < 4; ++fk) {
        const int colx = (fk & 1) * 32 + q * 8;
        const int rofs = fk >> 1;
        bf16x8 xh[4], xl[4], wh[4], wl[4];
        #pragma unroll
        for (int mt = 0; mt < 4; ++mt) {
            size_t xo = (size_t)(xrow0 + wrow + mt * 16 + c16 + rofs) * 64 + colx;
            xh[mt] = *(const bf16x8*)(XH + xo);
            xl[mt] = *(const bf16x8*)(XL + xo);
        }
        #pragma unroll
        for (int nt = 0; nt < 4; ++nt) {
            size_t wo = (size_t)((fk * 4 + nt) * 64 + lane) * 8;
            wh[nt] = *(const bf16x8*)(w1hb + wo);
            wl[nt] = *(const bf16x8*)(w1lb + wo);
        }
        #pragma unroll
        for (int nt = 0; nt < 4; ++nt)
            #pragma unroll
            for (int mt = 0; mt < 4; ++mt) {
                zT[nt][mt] = __builtin_amdgcn_mfma_f32_16x16x32_bf16(wh[nt], xh[mt], zT[nt][mt], 0, 0, 0);
                zT[nt][mt] = __builtin_amdgcn_mfma_f32_16x16x32_bf16(wh[nt], xl[mt], zT[nt][mt], 0, 0, 0);
                zT[nt][mt] = __builtin_amdgcn_mfma_f32_16x16x32_bf16(wl[nt], xh[mt], zT[nt][mt], 0, 0, 0);
            }
    }

    // ---- per-mt: finalize -> stage 2 -> epilogue, all in registers ----
    union U { bf16x8 v; unsigned u[4]; };
    const short* w2hb = W2H + (size_t)l * 4096;
    const short* w2lb = W2L + (size_t)l * 4096;
    const short* vhb  = VH  + (size_t)l * 4096;
    const short* vlb  = VL  + (size_t)l * 4096;
    const float b3l = b3[l];
    float po_keep = 0.f, pd_keep = 0.f;

    #pragma unroll
    for (int mt = 0; mt < 4; ++mt) {
        // finalize THIS mt: a1 = leaky(zT + xt*w1_last) -> pk frag dwords
        unsigned pkh[4][2], pkl[4][2];
        #pragma unroll
        for (int nt = 0; nt < 4; ++nt) {
            float4 wc = *(const float4*)(WLF + l * 64 + nt * 16 + q * 4);
            float w1c[4] = {wc.x, wc.y, wc.z, wc.w};
            #pragma unroll
            for (int p = 0; p < 2; ++p) {
                float v0 = zT[nt][mt][2*p]   + xt[mt] * w1c[2*p];
                float v1 = zT[nt][mt][2*p+1] + xt[mt] * w1c[2*p+1];
                float a0  = fmaxf(v0, 0.01f * v0);
                float a1v = fmaxf(v1, 0.01f * v1);
                pack2(a0, a1v, &pkh[nt][p], &pkl[nt][p]);
            }
        }

        // stage 2: za = a1@W2' + b2 (seeded, 3-pass), zm = mask@V (2-pass)
        f32x4 za[4], zm[4];
        #pragma unroll
        for (int gt = 0; gt < 4; ++gt) {
            float4 b2c = *(const float4*)(b2 + l * 64 + gt * 16 + q * 4);
            za[gt] = (f32x4){b2c.x, b2c.y, b2c.z, b2c.w};
            zm[gt] = (f32x4){0.f, 0.f, 0.f, 0.f};
        }
        #pragma unroll
        for (int kc2 = 0; kc2 < 2; ++kc2) {
            U ah, al;
            ah.u[0] = pkh[2*kc2  ][0]; ah.u[1] = pkh[2*kc2  ][1];
            ah.u[2] = pkh[2*kc2+1][0]; ah.u[3] = pkh[2*kc2+1][1];
            al.u[0] = pkl[2*kc2  ][0]; al.u[1] = pkl[2*kc2  ][1];
            al.u[2] = pkl[2*kc2+1][0]; al.u[3] = pkl[2*kc2+1][1];
            bf16x8 mk = maskone(ah.v);
            #pragma unroll
            for (int gt = 0; gt < 4; ++gt) {
                size_t wo = (size_t)((kc2 * 4 + gt) * 64 + lane) * 8;
                bf16x8 w2h = *(const bf16x8*)(w2hb + wo);
                bf16x8 w2l = *(const bf16x8*)(w2lb + wo);
                bf16x8 vh  = *(const bf16x8*)(vhb + wo);
                bf16x8 vl  = *(const bf16x8*)(vlb + wo);
                za[gt] = __builtin_amdgcn_mfma_f32_16x16x32_bf16(w2h, ah.v, za[gt], 0, 0, 0);
                za[gt] = __builtin_amdgcn_mfma_f32_16x16x32_bf16(w2h, al.v, za[gt], 0, 0, 0);
                za[gt] = __builtin_amdgcn_mfma_f32_16x16x32_bf16(w2l, ah.v, za[gt], 0, 0, 0);
                zm[gt] = __builtin_amdgcn_mfma_f32_16x16x32_bf16(vh,  mk,   zm[gt], 0, 0, 0);
                zm[gt] = __builtin_amdgcn_mfma_f32_16x16x32_bf16(vl,  mk,   zm[gt], 0, 0, 0);
            }
        }

        // epilogue: g = gt*16 + q*4 + r is lane-local (b2 already in za)
        float po = 0.f, pd = 0.f;
        #pragma unroll
        for (int gt = 0; gt < 4; ++gt) {
            float4 w3c = *(const float4*)(W3 + l * 64 + gt * 16 + q * 4);
            float4 rc  = *(const float4*)(RSV + l * 64 + gt * 16 + q * 4);
            float w3a[4] = {w3c.x, w3c.y, w3c.z, w3c.w};
            float rca[4] = {rc.x,  rc.y,  rc.z,  rc.w};
            #pragma unroll
            for (int r = 0; r < 4; ++r) {
                float zv = za[gt][r];
                float a2 = fmaxf(zv, 0.01f * zv);
                float zt = 0.99f * zm[gt][r] + 0.01f * rca[r];
                po += a2 * w3a[r];
                pd += (zv > 0.f ? w3a[r] : 0.01f * w3a[r]) * zt;
            }
        }
        po += __shfl_xor(po, 16);
        po += __shfl_xor(po, 32);
        pd += __shfl_xor(pd, 16);
        pd += __shfl_xor(pd, 32);
        if (q == mt) { po_keep = po; pd_keep = pd; }
    }

    const int n = nb + wrow + lane;         // lane == mt*16+c16 for mt==q
    out[(size_t)n * 64 + l] = po_keep + b3l;
    PD[(size_t)l * NTOT + n] = pd_keep;     // coalesced
}

extern "C" void kernel_launch(void* const* d_in, const int* in_sizes, int n_in,
                              void* d_out, int out_size, void* d_ws, size_t ws_size,
                              hipStream_t stream) {
    const float* x  = (const float*)d_in[0];
    const float* W1 = (const float*)d_in[1];
    const float* b1 = (const float*)d_in[2];
    const float* W2 = (const float*)d_in[3];
    const float* b2 = (const float*)d_in[4];
    const float* W3 = (const float*)d_in[5];
    const float* b3 = (const float*)d_in[6];
    float* out = (float*)d_out;
    char* ws = (char*)d_ws;

    short* XH   = (short*)(ws + OXH);
    short* XL   = (short*)(ws + OXL);
    short* W1Hp = (short*)(ws + OW1H);
    short* W1Lp = (short*)(ws + OW1L);
    short* W2Hp = (short*)(ws + OW2H);
    short* W2Lp = (short*)(ws + OW2L);
    short* VHp  = (short*)(ws + OVH);
    short* VLp  = (short*)(ws + OVL);
    float* WLFp = (float*)(ws + OWLF);
    float* RSVp = (float*)(ws + ORSV);
    float* PDp  = (float*)(ws + OPD);

    hipLaunchKernelGGL(prep_all, dim3(1026 + 384 + 64), dim3(256), 0, stream,
                       x, W1, W2, XH, XL, W1Hp, W1Lp, W2Hp, W2Lp, VHp, VLp,
                       WLFp, RSVp);
    dim3 grid(64 /*l*/, NTOT / 256 /*row tiles of 256*/);
    hipLaunchKernelGGL(np_main, grid, dim3(256), 0, stream,
                       x, b1, b2, W3, b3,
                       XH, XL, W1Hp, W1Lp, W2Hp, W2Lp, VHp, VLp,
                       WLFp, RSVp, PDp, out);
    hipLaunchKernelGGL(finish_logdet, dim3(NTOT / 256), dim3(256), 0, stream,
                       PDp, out + (size_t)NTOT * 64);
}

// Round 9
// 204.685 us; speedup vs baseline: 2.1028x; 1.1317x over previous
//
#include <hip/hip_runtime.h>
#include <math.h>

#define BB   16
#define TT   1026
#define LEN  1024
#define NTOT (BB*LEN)        // 16384
#define NX   (BB*TT*64)      // 1050624 floats in x
#define AP   68              // LDS act row stride in shorts (measured ~conflict-free)

typedef __attribute__((ext_vector_type(8))) short bf16x8;
typedef __attribute__((ext_vector_type(4))) float f32x4;

// ---- ws byte offsets ----
#define OXH   ((size_t)0)                     // XH: NX shorts
#define OXL   (OXH + (size_t)NX*2)            // XL: NX shorts
#define OW1H  (OXL + (size_t)NX*2)            // 64 l * 8192 shorts
#define OW1L  (OW1H + (size_t)64*8192*2)
#define OW2H  (OW1L + (size_t)64*8192*2)      // 64 l * 4096 shorts (canonical k-order)
#define OW2L  (OW2H + (size_t)64*4096*2)
#define OVH   (OW2L + (size_t)64*4096*2)      // V = w1l .* W2 (canonical k-order)
#define OVL   (OVH + (size_t)64*4096*2)
#define OWLF  (OVL + (size_t)64*4096*2)       // f32 [64][64] w1_last transposed
#define ORSV  (OWLF + (size_t)64*64*4)        // f32 [64*64]
#define OPD   (ORSV + (size_t)64*64*4)        // f32 [64][16384] dJ per l,n

__device__ __forceinline__ unsigned int rne16(unsigned int u) {
    return (u + 0x7FFFu + ((u >> 16) & 1u)) >> 16;
}
__device__ __forceinline__ void split2(float v, short* h, short* s) {
    unsigned int u  = __float_as_uint(v);
    unsigned int hi = rne16(u);
    float lof = v - __uint_as_float(hi << 16);
    *h = (short)hi;
    *s = (short)rne16(__float_as_uint(lof));
}
// mask frag: half = (a positive ? bf16(1.0) : 0). Exact {0,1} in bf16.
__device__ __forceinline__ bf16x8 maskone(bf16x8 a) {
    union { bf16x8 v; unsigned int u[4]; } A, M;
    A.v = a;
    #pragma unroll
    for (int j = 0; j < 4; ++j) {
        unsigned int t = (~A.u[j]) & 0x80008000u;   // sign==0 (positive) halves
        M.u[j] = (t >> 15) * 0x3F80u;               // per-half 1.0bf16
    }
    return M.v;
}

// ---- fused prep ----
// blocks [0,1026):   x -> XH/XL
// blocks [1026,1410): weight frags, canonical k-order; W2 branch also emits
//                     V = w1l .* W2 (split from the fp32 product)
// blocks [1410,1474): RSV (parallel, 256 thr) + WLF fp32 w1_last table
__global__ __launch_bounds__(256)
void prep_all(const float* __restrict__ x, const float* __restrict__ W1,
              const float* __restrict__ W2,
              short* __restrict__ XH, short* __restrict__ XL,
              short* __restrict__ W1H, short* __restrict__ W1L,
              short* __restrict__ W2H, short* __restrict__ W2L,
              short* __restrict__ VH,  short* __restrict__ VL,
              float* __restrict__ WLF, float* __restrict__ RSV)
{
    const int b = blockIdx.x, tid = threadIdx.x;
    if (b < 1026) {
        int i = (b * 256 + tid) * 4;
        float4 v = *(const float4*)(x + i);
        float vv[4] = {v.x, v.y, v.z, v.w};
        short hh[4], ll[4];
        #pragma unroll
        for (int j = 0; j < 4; ++j) split2(vv[j], &hh[j], &ll[j]);
        *(short4*)&XH[i] = make_short4(hh[0], hh[1], hh[2], hh[3]);
        *(short4*)&XL[i] = make_short4(ll[0], ll[1], ll[2], ll[3]);
    } else if (b < 1410) {
        int e = (b - 1026) * 256 + tid;          // 0..98303
        int l = e / 1536, r = e - l * 1536;
        if (r < 1024) {                           // W1 frag elem
            int fid = r >> 6, lane = r & 63;
            int fk = fid >> 2, nt = fid & 3;
            int h  = nt * 16 + (lane & 15);
            int f0 = fk * 32 + (lane >> 4) * 8;
            const float* src = W1 + (size_t)l * 8256 + h * 129 + f0;
            size_t o = (size_t)l * 8192 + (size_t)r * 8;
            #pragma unroll
            for (int j = 0; j < 8; ++j) {
                short h_, l_; split2(src[j], &h_, &l_);
                W1H[o + j] = h_; W1L[o + j] = l_;
            }
        } else {                                  // W2 + V frag elem (canonical)
            int r2 = r - 1024;
            int fid = r2 >> 6, lane = r2 & 63;
            int kc2 = fid >> 2, nt = fid & 3;
            int g  = nt * 16 + (lane & 15);
            int h0 = kc2 * 32 + (lane >> 4) * 8;
            const float* src = W2 + (size_t)l * 4096 + g * 64 + h0;
            const float* wlp = W1 + (size_t)l * 8256 + 128;  // wl[h] = wlp[h*129]
            size_t o = (size_t)l * 4096 + (size_t)r2 * 8;
            #pragma unroll
            for (int j = 0; j < 8; ++j) {
                float w2v = src[j];
                short h_, l_;
                split2(w2v, &h_, &l_);
                W2H[o + j] = h_; W2L[o + j] = l_;
                float vv = w2v * wlp[(size_t)(h0 + j) * 129];
                split2(vv, &h_, &l_);
                VH[o + j] = h_; VL[o + j] = l_;
            }
        }
    } else {
        const int l = b - 1410;
        const float* wlp = W1 + (size_t)l * 8256 + 128;
        int g = tid >> 2, part = tid & 3;
        const float* w2row = W2 + (size_t)l * 4096 + g * 64 + part * 16;
        float p = 0.f;
        #pragma unroll 4
        for (int hh = 0; hh < 16; ++hh)
            p += w2row[hh] * wlp[(size_t)(part * 16 + hh) * 129];
        p += __shfl_xor(p, 1);
        p += __shfl_xor(p, 2);
        if (part == 0) RSV[l * 64 + g] = p;
        if (tid < 64) WLF[l * 64 + tid] = wlp[(size_t)tid * 129];
    }
}

// logdet[n] = sum_l log|PD[l][n]|
__global__ __launch_bounds__(256)
void finish_logdet(const float* __restrict__ PD, float* __restrict__ logdet) {
    int i = blockIdx.x * 256 + threadIdx.x;      // grid exact: NTOT/256
    float acc = 0.f;
    #pragma unroll 8
    for (int l = 0; l < 64; ++l)
        acc += __logf(fabsf(PD[(size_t)l * NTOT + i]));
    logdet[i] = acc;
}

// r0 skeleton (proven 144.6us, register-pressure-safe via LDS a1 staging)
// + V-trick (zm 2-pass, -32 MFMA/wave) + b1/b2 seeds + WLF + maskone.
// Wave-private LDS, no __syncthreads. INVARIANT: wave wid touches ONLY
// shorts [wid*64*AP, (wid+1)*64*AP) of each array; epilogue scratch
// (float*)base + wid*2176 is exactly the wave's own 64 rows.
// HISTORY: fully-in-register variants (r2-r7) all spill (allocator caps
// arch VGPR at 128) or stall (scheduling clobbers). Tripwire: WRITE>60MB.
__global__ __launch_bounds__(256, 2)
void np_main(const float* __restrict__ x,
             const float* __restrict__ b1, const float* __restrict__ b2,
             const float* __restrict__ W3, const float* __restrict__ b3,
             const short* __restrict__ XH, const short* __restrict__ XL,
             const short* __restrict__ W1H, const short* __restrict__ W1L,
             const short* __restrict__ W2H, const short* __restrict__ W2L,
             const short* __restrict__ VH,  const short* __restrict__ VL,
             const float* __restrict__ WLF, const float* __restrict__ RSV,
             float* __restrict__ PD, float* __restrict__ out)
{
    __shared__ __align__(16) short a1h[256 * AP];
    __shared__ __align__(16) short a1l[256 * AP];

    const int l = blockIdx.x, tid = threadIdx.x;
    const int nb = blockIdx.y * 256;
    const int bb = nb >> 10, t0 = nb & 1023;
    const int lane = tid & 63, wid = tid >> 6;
    const int q = lane >> 4, c16 = lane & 15;
    const int wrow = wid * 64;                   // wave's 64 rows within block
    const size_t xrow0 = (size_t)(bb * TT + t0);

    // ---- stage 1: z1[64rows x 64h] = x_lags @ W1' + b1 (seeded) ----
    f32x4 z1[4][4];
    #pragma unroll
    for (int nt = 0; nt < 4; ++nt) {
        float b1v = b1[l * 64 + nt * 16 + c16];
        #pragma unroll
        for (int mt = 0; mt < 4; ++mt)
            z1[mt][nt] = (f32x4){b1v, b1v, b1v, b1v};
    }

    const short* w1hb = W1H + (size_t)l * 8192;
    const short* w1lb = W1L + (size_t)l * 8192;
    #pragma unroll
    for (int fk = 0; fk < 4; ++fk) {
        const int colx = (fk & 1) * 32 + q * 8;
        const int rofs = fk >> 1;
        bf16x8 ah[4], al[4], bh[4], bl[4];
        #pragma unroll
        for (int mt = 0; mt < 4; ++mt) {
            size_t xo = (xrow0 + wrow + mt * 16 + c16 + rofs) * 64 + colx;
            ah[mt] = *(const bf16x8*)(XH + xo);
            al[mt] = *(const bf16x8*)(XL + xo);
        }
        #pragma unroll
        for (int nt = 0; nt < 4; ++nt) {
            size_t wo = (size_t)((fk * 4 + nt) * 64 + lane) * 8;
            bh[nt] = *(const bf16x8*)(w1hb + wo);
            bl[nt] = *(const bf16x8*)(w1lb + wo);
        }
        #pragma unroll
        for (int mt = 0; mt < 4; ++mt)
            #pragma unroll
            for (int nt = 0; nt < 4; ++nt) {
                z1[mt][nt] = __builtin_amdgcn_mfma_f32_16x16x32_bf16(ah[mt], bh[nt], z1[mt][nt], 0, 0, 0);
                z1[mt][nt] = __builtin_amdgcn_mfma_f32_16x16x32_bf16(al[mt], bh[nt], z1[mt][nt], 0, 0, 0);
                z1[mt][nt] = __builtin_amdgcn_mfma_f32_16x16x32_bf16(ah[mt], bl[nt], z1[mt][nt], 0, 0, 0);
            }
    }

    // finalize z1 fp32: + x_t*w1_last (b1 already seeded); write a1 hi/lo
    float w1lc[4];
    #pragma unroll
    for (int nt = 0; nt < 4; ++nt)
        w1lc[nt] = WLF[l * 64 + nt * 16 + c16];
    #pragma unroll
    for (int mt = 0; mt < 4; ++mt)
        #pragma unroll
        for (int r = 0; r < 4; ++r) {
            int mrow = wrow + mt * 16 + q * 4 + r;
            float xt = x[(xrow0 + mrow + 2) * 64 + l];
            #pragma unroll
            for (int nt = 0; nt < 4; ++nt) {
                float z  = z1[mt][nt][r] + xt * w1lc[nt];
                float av = z > 0.f ? z : 0.01f * z;
                int idx = mrow * AP + nt * 16 + c16;
                short h_, s_; split2(av, &h_, &s_);
                a1h[idx] = h_;
                a1l[idx] = s_;
            }
        }

    // ---- stage 2 (wave-private, no barrier):
    //   z2a = a1 @ W2' + b2 (seeded; 3-pass hi/lo)
    //   z2m = mask{0,1} @ V'  (2-pass; V = w1l.*W2 split from fp32 product)
    f32x4 z2a[4][4], z2m[4][4];
    #pragma unroll
    for (int nt = 0; nt < 4; ++nt) {
        float b2v = b2[l * 64 + nt * 16 + c16];
        #pragma unroll
        for (int mt = 0; mt < 4; ++mt) {
            z2a[mt][nt] = (f32x4){b2v, b2v, b2v, b2v};
            z2m[mt][nt] = (f32x4){0.f, 0.f, 0.f, 0.f};
        }
    }
    const short* w2hb = W2H + (size_t)l * 4096;
    const short* w2lb = W2L + (size_t)l * 4096;
    const short* vhb  = VH  + (size_t)l * 4096;
    const short* vlb  = VL  + (size_t)l * 4096;
    #pragma unroll
    for (int kc2 = 0; kc2 < 2; ++kc2) {
        bf16x8 ah2[4], al2[4];
        #pragma unroll
        for (int mt = 0; mt < 4; ++mt) {
            int ao = (wrow + mt * 16 + c16) * AP + kc2 * 32 + q * 8;
            ah2[mt] = *(const bf16x8*)&a1h[ao];
            al2[mt] = *(const bf16x8*)&a1l[ao];
        }
        {   // za passes: W2 frags live only here
            bf16x8 wh[4], wl2[4];
            #pragma unroll
            for (int nt = 0; nt < 4; ++nt) {
                size_t wo = (size_t)((kc2 * 4 + nt) * 64 + lane) * 8;
                wh[nt]  = *(const bf16x8*)(w2hb + wo);
                wl2[nt] = *(const bf16x8*)(w2lb + wo);
            }
            #pragma unroll
            for (int mt = 0; mt < 4; ++mt)
                #pragma unroll
                for (int nt = 0; nt < 4; ++nt) {
                    z2a[mt][nt] = __builtin_amdgcn_mfma_f32_16x16x32_bf16(ah2[mt], wh[nt],  z2a[mt][nt], 0, 0, 0);
                    z2a[mt][nt] = __builtin_amdgcn_mfma_f32_16x16x32_bf16(al2[mt], wh[nt],  z2a[mt][nt], 0, 0, 0);
                    z2a[mt][nt] = __builtin_amdgcn_mfma_f32_16x16x32_bf16(ah2[mt], wl2[nt], z2a[mt][nt], 0, 0, 0);
                }
        }
        {   // zm passes: V frags reuse the (now dead) W2 frag registers
            bf16x8 vh2[4], vl2[4];
            #pragma unroll
            for (int nt = 0; nt < 4; ++nt) {
                size_t wo = (size_t)((kc2 * 4 + nt) * 64 + lane) * 8;
                vh2[nt] = *(const bf16x8*)(vhb + wo);
                vl2[nt] = *(const bf16x8*)(vlb + wo);
            }
            #pragma unroll
            for (int mt = 0; mt < 4; ++mt) {
                bf16x8 mk = maskone(ah2[mt]);
                #pragma unroll
                for (int nt = 0; nt < 4; ++nt) {
                    z2m[mt][nt] = __builtin_amdgcn_mfma_f32_16x16x32_bf16(mk, vh2[nt], z2m[mt][nt], 0, 0, 0);
                    z2m[mt][nt] = __builtin_amdgcn_mfma_f32_16x16x32_bf16(mk, vl2[nt], z2m[mt][nt], 0, 0, 0);
                }
            }
        }
    }

    // ---- epilogue: per-row dot with w3, via wave-private LDS transpose ----
    float w3c[4], rsv[4];
    #pragma unroll
    for (int nt = 0; nt < 4; ++nt) {
        int g = nt * 16 + c16;
        w3c[nt] = W3[l * 64 + g];
        rsv[nt] = RSV[l * 64 + g];
    }
    float* spo = (float*)a1h + wid * 2176;   // wave's own quarter (2176 floats)
    float* spd = (float*)a1l + wid * 2176;
    #pragma unroll
    for (int mt = 0; mt < 4; ++mt)
        #pragma unroll
        for (int r = 0; r < 4; ++r) {
            float po = 0.f, pd = 0.f;
            #pragma unroll
            for (int nt = 0; nt < 4; ++nt) {
                float zv = z2a[mt][nt][r];                 // b2 already seeded
                float a2 = zv > 0.f ? zv : 0.01f * zv;
                float d2 = zv > 0.f ? 1.0f : 0.01f;
                float zt = 0.01f * rsv[nt] + 0.99f * z2m[mt][nt][r];
                po += a2 * w3c[nt];
                pd += d2 * zt * w3c[nt];
            }
            int row = mt * 16 + q * 4 + r;   // 0..63
            spo[row * 17 + c16] = po;
            spd[row * 17 + c16] = pd;
        }
    __threadfence_block();

    {
        float so = 0.f, sd = 0.f;
        #pragma unroll
        for (int j = 0; j < 16; ++j) {
            so += spo[lane * 17 + j];
            sd += spd[lane * 17 + j];
        }
        int n = nb + wrow + lane;
        out[(size_t)n * 64 + l] = so + b3[l];
        PD[(size_t)l * NTOT + n] = sd;       // coalesced; log+sum in finish kernel
    }
}

extern "C" void kernel_launch(void* const* d_in, const int* in_sizes, int n_in,
                              void* d_out, int out_size, void* d_ws, size_t ws_size,
                              hipStream_t stream) {
    const float* x  = (const float*)d_in[0];
    const float* W1 = (const float*)d_in[1];
    const float* b1 = (const float*)d_in[2];
    const float* W2 = (const float*)d_in[3];
    const float* b2 = (const float*)d_in[4];
    const float* W3 = (const float*)d_in[5];
    const float* b3 = (const float*)d_in[6];
    float* out = (float*)d_out;
    char* ws = (char*)d_ws;

    short* XH   = (short*)(ws + OXH);
    short* XL   = (short*)(ws + OXL);
    short* W1Hp = (short*)(ws + OW1H);
    short* W1Lp = (short*)(ws + OW1L);
    short* W2Hp = (short*)(ws + OW2H);
    short* W2Lp = (short*)(ws + OW2L);
    short* VHp  = (short*)(ws + OVH);
    short* VLp  = (short*)(ws + OVL);
    float* WLFp = (float*)(ws + OWLF);
    float* RSVp = (float*)(ws + ORSV);
    float* PDp  = (float*)(ws + OPD);

    hipLaunchKernelGGL(prep_all, dim3(1026 + 384 + 64), dim3(256), 0, stream,
                       x, W1, W2, XH, XL, W1Hp, W1Lp, W2Hp, W2Lp, VHp, VLp,
                       WLFp, RSVp);
    dim3 grid(64 /*l*/, NTOT / 256 /*n tiles of 256*/);
    hipLaunchKernelGGL(np_main, grid, dim3(256), 0, stream,
                       x, b1, b2, W3, b3,
                       XH, XL, W1Hp, W1Lp, W2Hp, W2Lp, VHp, VLp,
                       WLFp, RSVp, PDp, out);
    hipLaunchKernelGGL(finish_logdet, dim3(NTOT / 256), dim3(256), 0, stream,
                       PDp, out + (size_t)NTOT * 64);
}